// Round 10
// baseline (207.059 us; speedup 1.0000x reference)
//
#include <hip/hip_runtime.h>
#include <hip/hip_bf16.h>

#define BB 4
#define SS 2048
#define DD 1024
#define HH 16
#define HDD 64
#define MM (BB*SS)   // 8192

using bf16x8  = __attribute__((ext_vector_type(8))) short;
using f32x4   = __attribute__((ext_vector_type(4))) float;
using f32x16  = __attribute__((ext_vector_type(16))) float;
using ushort8 = __attribute__((ext_vector_type(8))) unsigned short;
using ushort4v= __attribute__((ext_vector_type(4))) unsigned short;
using uint2v  = __attribute__((ext_vector_type(2))) unsigned int;
using uint4v  = __attribute__((ext_vector_type(4))) unsigned int;

#if __has_builtin(__builtin_amdgcn_exp2f)
#define EXP2(x) __builtin_amdgcn_exp2f(x)
#else
#define EXP2(x) exp2f(x)
#endif

__device__ __forceinline__ unsigned short f2bf(float x) {
    unsigned u = __builtin_bit_cast(unsigned, x);
    u += 0x7FFFu + ((u >> 16) & 1u);          // RNE
    return (unsigned short)(u >> 16);
}

__device__ __forceinline__ unsigned int cvtpk(float lo, float hi) {
    unsigned int r;
    asm("v_cvt_pk_bf16_f32 %0, %1, %2" : "=v"(r) : "v"(lo), "v"(hi));
    return r;
}

// permlane32_swap: ONLY on provably-distinct live values (PV w-words).
// Never on a value and its own copy (rounds 4/5 aliasing bug).
#define PSWAP(a, b) asm("v_permlane32_swap_b32 %0, %1" : "+v"(a), "+v"(b))

__device__ __forceinline__ void load_lds16(const void* g, void* l) {
    __builtin_amdgcn_global_load_lds(
        (const __attribute__((address_space(1))) void*)g,
        (__attribute__((address_space(3))) void*)l, 16, 0, 0);
}

// ---------------------------------------------------------------------------
// Merged f32 -> bf16 conversion: z 0..7 = x (8 chunks), z 8..11 = Wq,Wk,Wv,Wo.
// Wq gets 0.125*log2(e): exp2(S') == exp(q.k/8).  2048 elems/block.
// ---------------------------------------------------------------------------
__global__ __launch_bounds__(256) void cvt_all(const float* __restrict__ x,
                                               const float* __restrict__ wq,
                                               const float* __restrict__ wk,
                                               const float* __restrict__ wv,
                                               const float* __restrict__ wo,
                                               unsigned short* __restrict__ ox,
                                               unsigned short* __restrict__ oq,
                                               unsigned short* __restrict__ ok,
                                               unsigned short* __restrict__ ov,
                                               unsigned short* __restrict__ oo) {
    const int z = blockIdx.y;
    const float* src;
    unsigned short* dst;
    float scale = 1.0f;
    size_t base;
    if (z < 8)       { src = x;  dst = ox; base = (size_t)z * 512 * 2048; }
    else if (z == 8) { src = wq; dst = oq; base = 0; scale = 0.18033688011112042f; }
    else if (z == 9) { src = wk; dst = ok; base = 0; }
    else if (z == 10){ src = wv; dst = ov; base = 0; }
    else             { src = wo; dst = oo; base = 0; }
    size_t i = base + ((size_t)blockIdx.x * 256 + threadIdx.x) * 8;
    float4 a = *(const float4*)(src + i);
    float4 b = *(const float4*)(src + i + 4);
    ushort8 r;
    r[0] = f2bf(a.x*scale); r[1] = f2bf(a.y*scale); r[2] = f2bf(a.z*scale); r[3] = f2bf(a.w*scale);
    r[4] = f2bf(b.x*scale); r[5] = f2bf(b.y*scale); r[6] = f2bf(b.z*scale); r[7] = f2bf(b.w*scale);
    *(ushort8*)(dst + i) = r;
}

// ---------------------------------------------------------------------------
// Shared GEMM body (m97 structure), XCD-swizzled.  LAYOUT 0: f32 C[M][1024];
// 1: bf16 [B,H,S,HD]; 2: bf16 V^T [B,H,HD,S].
// ---------------------------------------------------------------------------
template<int LAYOUT>
__device__ __forceinline__ void gemm_body(const unsigned short* __restrict__ A,
                                          const unsigned short* __restrict__ W,
                                          void* __restrict__ Cout,
                                          unsigned short* As, unsigned short* Bs) {
    const int t    = threadIdx.x;
    const int lane = t & 63, wid = t >> 6;
    const int wr   = wid >> 1, wc = wid & 1;
    const int lrow = lane & 15, lkg = lane >> 4;
    const int lid  = blockIdx.y * 8 + blockIdx.x;
    const int ord  = (lid & 7) * 64 + (lid >> 3);
    const int row0 = (ord >> 3) * 128, col0 = (ord & 7) * 128;

    f32x4 acc[4][4];
    #pragma unroll
    for (int m = 0; m < 4; ++m)
        #pragma unroll
        for (int n = 0; n < 4; ++n) acc[m][n] = (f32x4){0.f, 0.f, 0.f, 0.f};

    const int c0 = t, c1 = t + 256;
    const unsigned short* Ag0 = A + (size_t)(row0 + (c0 >> 2)) * DD + (c0 & 3) * 8;
    const unsigned short* Ag1 = A + (size_t)(row0 + (c1 >> 2)) * DD + (c1 & 3) * 8;
    const unsigned short* Wg0 = W + (size_t)(col0 + (c0 >> 2)) * DD + (c0 & 3) * 8;
    const unsigned short* Wg1 = W + (size_t)(col0 + (c1 >> 2)) * DD + (c1 & 3) * 8;

    auto stage = [&](int buf, int k0) {
        load_lds16(Ag0 + k0, &As[buf*128*32 + c0 * 8]);
        load_lds16(Ag1 + k0, &As[buf*128*32 + c1 * 8]);
        load_lds16(Wg0 + k0, &Bs[buf*128*32 + c0 * 8]);
        load_lds16(Wg1 + k0, &Bs[buf*128*32 + c1 * 8]);
    };

    stage(0, 0);
    __syncthreads();
    for (int kt = 0; kt < DD / 32; ++kt) {
        const int cur = kt & 1;
        if (kt + 1 < DD / 32) stage(cur ^ 1, (kt + 1) * 32);
        bf16x8 af[4], bfr[4];
        #pragma unroll
        for (int m = 0; m < 4; ++m)
            af[m] = *(const bf16x8*)&As[cur*128*32 + (wr*64 + m*16 + lrow) * 32 + lkg*8];
        #pragma unroll
        for (int n = 0; n < 4; ++n)
            bfr[n] = *(const bf16x8*)&Bs[cur*128*32 + (wc*64 + n*16 + lrow) * 32 + lkg*8];
        __builtin_amdgcn_s_setprio(1);
        #pragma unroll
        for (int m = 0; m < 4; ++m)
            #pragma unroll
            for (int n = 0; n < 4; ++n)
                acc[m][n] = __builtin_amdgcn_mfma_f32_16x16x32_bf16(af[m], bfr[n], acc[m][n], 0, 0, 0);
        __builtin_amdgcn_s_setprio(0);
        __syncthreads();
    }

    #pragma unroll
    for (int m = 0; m < 4; ++m) {
        #pragma unroll
        for (int n = 0; n < 4; ++n) {
            if (LAYOUT == 2) {
                int gm0 = row0 + wr*64 + m*16 + lkg*4;
                int gn  = col0 + wc*64 + n*16 + lrow;
                int b_ = gm0 >> 11, s0 = gm0 & 2047;
                int h_ = gn >> 6,  hd = gn & 63;
                ushort4v hv;
                hv[0] = f2bf(acc[m][n][0]); hv[1] = f2bf(acc[m][n][1]);
                hv[2] = f2bf(acc[m][n][2]); hv[3] = f2bf(acc[m][n][3]);
                *(ushort4v*)&((unsigned short*)Cout)[(((size_t)b_*HH + h_)*HDD + hd)*SS + s0] = hv;
            } else {
                #pragma unroll
                for (int j = 0; j < 4; ++j) {
                    int gm = row0 + wr*64 + m*16 + lkg*4 + j;
                    int gn = col0 + wc*64 + n*16 + lrow;
                    float v = acc[m][n][j];
                    if (LAYOUT == 1) {
                        int b_ = gm >> 11, s_ = gm & 2047;
                        int h_ = gn >> 6,  hd = gn & 63;
                        ((unsigned short*)Cout)[(((size_t)b_*HH + h_)*SS + s_)*HDD + hd] = f2bf(v);
                    } else {
                        ((float*)Cout)[(size_t)gm * DD + gn] = v;
                    }
                }
            }
        }
    }
}

__global__ __launch_bounds__(256) void gemm_qkv(const unsigned short* __restrict__ A,
                                                const unsigned short* __restrict__ Wq,
                                                const unsigned short* __restrict__ Wk,
                                                const unsigned short* __restrict__ Wv,
                                                unsigned short* __restrict__ Q,
                                                unsigned short* __restrict__ K,
                                                unsigned short* __restrict__ V) {
    __shared__ unsigned short As[2*128*32];
    __shared__ unsigned short Bs[2*128*32];
    const int z = blockIdx.z;
    if (z == 2)      gemm_body<2>(A, Wv, V, As, Bs);
    else if (z == 1) gemm_body<1>(A, Wk, K, As, Bs);
    else             gemm_body<1>(A, Wq, Q, As, Bs);
}

__global__ __launch_bounds__(256) void gemm_proj(const unsigned short* __restrict__ A,
                                                 const unsigned short* __restrict__ W,
                                                 float* __restrict__ C) {
    __shared__ unsigned short As[2*128*32];
    __shared__ unsigned short Bs[2*128*32];
    gemm_body<0>(A, W, C, As, Bs);
}

// ---------------------------------------------------------------------------
// Flash attention v8b: v8 (KVBLK=128 staged, two sequential 64-key halves)
// with the round-9 bug fixed: K half-tile stride is 64 rows x 128 B = 8192 B
// (was h2*16384 = the whole K buffer -> h2=1 read the other double-buffer).
// ---------------------------------------------------------------------------
__global__ __launch_bounds__(256, 2) void flash_mfma8(const unsigned short* __restrict__ Qg,
                                                      const unsigned short* __restrict__ Kg,
                                                      const unsigned short* __restrict__ Vtg,
                                                      float* __restrict__ outf,
                                                      unsigned short* __restrict__ outb) {
    __shared__ unsigned short Ks[2][128*64];
    __shared__ unsigned short Vs[2][2*64*64];
    const int t   = threadIdx.x, lane = t & 63, wid = t >> 6;
    const int l31 = lane & 31;
    const int hi  = lane >> 5;
    const int lid = blockIdx.y * 8 + blockIdx.x;
    const int ord = (lid & 7) * 64 + (lid >> 3);
    const int bh  = ord >> 3, b_ = bh >> 4, h_ = bh & 15;
    const int qA  = (ord & 7) * 256 + wid * 32;    // group A rows; B = qA + 128

    const unsigned short* Qb = Qg  + (size_t)bh * SS * HDD;
    const unsigned short* Kb = Kg  + (size_t)bh * SS * HDD;
    const unsigned short* Vb = Vtg + (size_t)bh * HDD * SS;

    bf16x8 qfA[4], qfB[4];
    #pragma unroll
    for (int ks = 0; ks < 4; ++ks) {
        qfA[ks] = *(const bf16x8*)&Qb[(size_t)(qA + l31) * HDD + ks*16 + hi*8];
        qfB[ks] = *(const bf16x8*)&Qb[(size_t)(qA + 128 + l31) * HDD + ks*16 + hi*8];
    }

    f32x16 osA0, osA1, osB0, osB1, sumA, sumB, z;
    #pragma unroll
    for (int r = 0; r < 16; ++r) {
        osA0[r] = 0.f; osA1[r] = 0.f; osB0[r] = 0.f; osB1[r] = 0.f;
        sumA[r] = 0.f; sumB[r] = 0.f; z[r] = 0.f;
    }

    bf16x8 onesf;
    #pragma unroll
    for (int e = 0; e < 8; ++e) onesf[e] = (short)0x3F80;   // bf16 1.0

    // staging: per 128-key tile, K = 1024 chunks of 16B, V = 1024 chunks.
    unsigned sbK[4], sbV[4];
    const unsigned short* Kg4[4];
    const unsigned short* Vg4[4];
    #pragma unroll
    for (int i = 0; i < 4; ++i) {
        const int c = t + 256*i;                    // 0..1023
        sbK[i] = ((unsigned)(c << 4)) ^ ((((unsigned)c >> 3) & 7u) << 4);
        const int half = c >> 9, cv = c & 511;      // V: half-tile + within
        sbV[i] = (unsigned)(half * 8192)
               + (((unsigned)(cv << 4)) ^ ((((unsigned)cv >> 3) & 7u) << 4));
        Kg4[i] = Kb + 8*c;                          // row c>>3, col8 c&7 of K tile
        Vg4[i] = Vb + (size_t)(cv >> 3) * SS + half*64 + (cv & 7) * 8;
    }
    const unsigned xs = ((unsigned)(l31 & 7)) << 4;

    bf16x8 kr[4], vr[4];
    #pragma unroll
    for (int i = 0; i < 4; ++i) {
        kr[i] = *(const bf16x8*)Kg4[i];
        vr[i] = *(const bf16x8*)Vg4[i];
        *(bf16x8*)((char*)&Ks[0][0] + sbK[i]) = kr[i];
        *(bf16x8*)((char*)&Vs[0][0] + sbV[i]) = vr[i];
    }
    __syncthreads();

    for (int kt = 0; kt < SS/128; ++kt) {
        const int cur = kt & 1;
        if (kt + 1 < SS/128) {                      // issue next-tile loads early
            #pragma unroll
            for (int i = 0; i < 4; ++i) {
                kr[i] = *(const bf16x8*)(Kg4[i] + (size_t)(kt+1)*8192);
                vr[i] = *(const bf16x8*)(Vg4[i] + (kt+1)*128);
            }
        }

        #pragma unroll
        for (int h2 = 0; h2 < 2; ++h2) {            // two 64-key halves
            const char* Kc = (const char*)&Ks[cur][0] + h2 * 8192;  // 64 rows x 128 B
            const char* Vc = (const char*)&Vs[cur][0] + h2 * 8192;

            // S'^T = mfma(K, Q): each kf pair feeds all 4 accumulators
            f32x16 saA0, saA1, saB0, saB1;
            __builtin_amdgcn_s_setprio(1);
            #pragma unroll
            for (int ks = 0; ks < 4; ++ks) {
                const unsigned cb = ks*32 + hi*16;
                bf16x8 kf0 = *(const bf16x8*)(Kc + (((unsigned)(l31*128)      + cb) ^ xs));
                bf16x8 kf1 = *(const bf16x8*)(Kc + (((unsigned)((32+l31)*128) + cb) ^ xs));
                if (ks == 0) {
                    saA0 = __builtin_amdgcn_mfma_f32_32x32x16_bf16(kf0, qfA[0], z, 0, 0, 0);
                    saA1 = __builtin_amdgcn_mfma_f32_32x32x16_bf16(kf1, qfA[0], z, 0, 0, 0);
                    saB0 = __builtin_amdgcn_mfma_f32_32x32x16_bf16(kf0, qfB[0], z, 0, 0, 0);
                    saB1 = __builtin_amdgcn_mfma_f32_32x32x16_bf16(kf1, qfB[0], z, 0, 0, 0);
                } else {
                    saA0 = __builtin_amdgcn_mfma_f32_32x32x16_bf16(kf0, qfA[ks], saA0, 0, 0, 0);
                    saA1 = __builtin_amdgcn_mfma_f32_32x32x16_bf16(kf1, qfA[ks], saA1, 0, 0, 0);
                    saB0 = __builtin_amdgcn_mfma_f32_32x32x16_bf16(kf0, qfB[ks], saB0, 0, 0, 0);
                    saB1 = __builtin_amdgcn_mfma_f32_32x32x16_bf16(kf1, qfB[ks], saB1, 0, 0, 0);
                }
            }
            __builtin_amdgcn_s_setprio(0);

            // P = exp2(S') packed straight to bf16
            unsigned int pkA0[4][2], pkA1[4][2], pkB0[4][2], pkB1[4][2];
            #pragma unroll
            for (int a = 0; a < 4; ++a) {
                #pragma unroll
                for (int h = 0; h < 2; ++h) {
                    pkA0[a][h] = cvtpk(EXP2(saA0[4*a + 2*h]), EXP2(saA0[4*a + 2*h + 1]));
                    pkA1[a][h] = cvtpk(EXP2(saA1[4*a + 2*h]), EXP2(saA1[4*a + 2*h + 1]));
                    pkB0[a][h] = cvtpk(EXP2(saB0[4*a + 2*h]), EXP2(saB0[4*a + 2*h + 1]));
                    pkB1[a][h] = cvtpk(EXP2(saB1[4*a + 2*h]), EXP2(saB1[4*a + 2*h + 1]));
                }
            }

            __builtin_amdgcn_s_setprio(1);
            #pragma unroll
            for (int ksg = 0; ksg < 4; ++ksg) {
                const int ks2 = (ksg & 1) * 2;
                unsigned int a0, a1, a2, a3, b0, b1, b2, b3;
                if ((ksg >> 1) == 0) {
                    a0 = pkA0[ks2][0]; a2 = pkA0[ks2+1][0]; a1 = pkA0[ks2][1]; a3 = pkA0[ks2+1][1];
                    b0 = pkB0[ks2][0]; b2 = pkB0[ks2+1][0]; b1 = pkB0[ks2][1]; b3 = pkB0[ks2+1][1];
                } else {
                    a0 = pkA1[ks2][0]; a2 = pkA1[ks2+1][0]; a1 = pkA1[ks2][1]; a3 = pkA1[ks2+1][1];
                    b0 = pkB1[ks2][0]; b2 = pkB1[ks2+1][0]; b1 = pkB1[ks2][1]; b3 = pkB1[ks2+1][1];
                }
                PSWAP(a0, a2); PSWAP(a1, a3);
                PSWAP(b0, b2); PSWAP(b1, b3);
                uint4v wa = {a0, a1, a2, a3};
                uint4v wb = {b0, b1, b2, b3};
                bf16x8 pfA = __builtin_bit_cast(bf16x8, wa);
                bf16x8 pfB = __builtin_bit_cast(bf16x8, wb);
                const unsigned cb = ksg*32 + hi*16;
                bf16x8 vf0 = *(const bf16x8*)(Vc + (((unsigned)(l31*128)      + cb) ^ xs));
                bf16x8 vf1 = *(const bf16x8*)(Vc + (((unsigned)((32+l31)*128) + cb) ^ xs));
                osA0 = __builtin_amdgcn_mfma_f32_32x32x16_bf16(vf0, pfA, osA0, 0, 0, 0);
                osA1 = __builtin_amdgcn_mfma_f32_32x32x16_bf16(vf1, pfA, osA1, 0, 0, 0);
                osB0 = __builtin_amdgcn_mfma_f32_32x32x16_bf16(vf0, pfB, osB0, 0, 0, 0);
                osB1 = __builtin_amdgcn_mfma_f32_32x32x16_bf16(vf1, pfB, osB1, 0, 0, 0);
                sumA = __builtin_amdgcn_mfma_f32_32x32x16_bf16(onesf, pfA, sumA, 0, 0, 0);
                sumB = __builtin_amdgcn_mfma_f32_32x32x16_bf16(onesf, pfB, sumB, 0, 0, 0);
            }
            __builtin_amdgcn_s_setprio(0);
        }

        if (kt + 1 < SS/128) {                      // write next tile (other buffer)
            char* Kn = (char*)&Ks[cur ^ 1][0];
            char* Vn = (char*)&Vs[cur ^ 1][0];
            #pragma unroll
            for (int i = 0; i < 4; ++i) {
                *(bf16x8*)(Kn + sbK[i]) = kr[i];
                *(bf16x8*)(Vn + sbV[i]) = vr[i];
            }
        }
        __syncthreads();
    }

    // epilogue: L[q] = any element of sum acc (all identical by construction)
    #pragma unroll
    for (int g = 0; g < 2; ++g) {
        const float invl = 1.0f / (g == 0 ? sumA[0] : sumB[0]);
        const int   s_   = qA + (g ? 128 : 0) + l31;
        float*          po = outf + (((size_t)b_ * SS + s_) * HH + h_) * HDD;
        unsigned short* pb = outb + (((size_t)b_ * SS + s_) * HH + h_) * HDD;
        #pragma unroll
        for (int a = 0; a < 4; ++a) {
            {
                const f32x16& o = g == 0 ? osA0 : osB0;
                const int d0 = 8*a + 4*hi;
                float4 v; v.x = o[4*a+0]*invl; v.y = o[4*a+1]*invl;
                          v.z = o[4*a+2]*invl; v.w = o[4*a+3]*invl;
                *(float4*)&po[d0] = v;
                uint2v hv; hv[0] = cvtpk(v.x, v.y); hv[1] = cvtpk(v.z, v.w);
                *(uint2v*)&pb[d0] = hv;
            }
            {
                const f32x16& o = g == 0 ? osA1 : osB1;
                const int d0 = 32 + 8*a + 4*hi;
                float4 v; v.x = o[4*a+0]*invl; v.y = o[4*a+1]*invl;
                          v.z = o[4*a+2]*invl; v.w = o[4*a+3]*invl;
                *(float4*)&po[d0] = v;
                uint2v hv; hv[0] = cvtpk(v.x, v.y); hv[1] = cvtpk(v.z, v.w);
                *(uint2v*)&pb[d0] = hv;
            }
        }
    }
}

extern "C" void kernel_launch(void* const* d_in, const int* in_sizes, int n_in,
                              void* d_out, int out_size, void* d_ws, size_t ws_size,
                              hipStream_t stream) {
    const float* x  = (const float*)d_in[0];
    const float* Wq = (const float*)d_in[1];
    const float* Wk = (const float*)d_in[2];
    const float* Wv = (const float*)d_in[3];
    const float* Wo = (const float*)d_in[4];
    float* out      = (float*)d_out;
    float* per_head = out + (size_t)MM * DD;

    unsigned short* ws   = (unsigned short*)d_ws;
    const size_t NE = (size_t)MM * DD;        // 8M elements
    unsigned short* Qbf  = ws;
    unsigned short* Kbf  = Qbf + NE;
    unsigned short* Vbf  = Kbf + NE;          // V^T [B,H,HD,S]
    unsigned short* xbf  = Vbf + NE;
    unsigned short* wqbf = xbf + NE;
    unsigned short* wkbf = wqbf + (size_t)DD * DD;
    unsigned short* wvbf = wkbf + (size_t)DD * DD;
    unsigned short* wobf = wvbf + (size_t)DD * DD;
    unsigned short* cbf  = wobf + (size_t)DD * DD;

    cvt_all<<<dim3(512, 12), 256, 0, stream>>>(x, Wq, Wk, Wv, Wo,
                                               xbf, wqbf, wkbf, wvbf, wobf);

    gemm_qkv<<<dim3(DD / 128, MM / 128, 3), 256, 0, stream>>>(xbf, wqbf, wkbf, wvbf,
                                                              Qbf, Kbf, Vbf);

    flash_mfma8<<<dim3(8, BB * HH), 256, 0, stream>>>(Qbf, Kbf, Vbf, per_head, cbf);

    gemm_proj<<<dim3(DD / 128, MM / 128), 256, 0, stream>>>(cbf, wobf, out);
}

// Round 11
// 190.991 us; speedup vs baseline: 1.0841x; 1.0841x over previous
//
#include <hip/hip_runtime.h>
#include <hip/hip_bf16.h>

#define BB 4
#define SS 2048
#define DD 1024
#define HH 16
#define HDD 64
#define MM (BB*SS)   // 8192

using bf16x8  = __attribute__((ext_vector_type(8))) short;
using f32x4   = __attribute__((ext_vector_type(4))) float;
using f32x16  = __attribute__((ext_vector_type(16))) float;
using ushort8 = __attribute__((ext_vector_type(8))) unsigned short;
using ushort4v= __attribute__((ext_vector_type(4))) unsigned short;
using uint4v  = __attribute__((ext_vector_type(4))) unsigned int;

#if __has_builtin(__builtin_amdgcn_exp2f)
#define EXP2(x) __builtin_amdgcn_exp2f(x)
#else
#define EXP2(x) exp2f(x)
#endif

__device__ __forceinline__ unsigned short f2bf(float x) {
    unsigned u = __builtin_bit_cast(unsigned, x);
    u += 0x7FFFu + ((u >> 16) & 1u);          // RNE
    return (unsigned short)(u >> 16);
}

__device__ __forceinline__ unsigned int cvtpk(float lo, float hi) {
    unsigned int r;
    asm("v_cvt_pk_bf16_f32 %0, %1, %2" : "=v"(r) : "v"(lo), "v"(hi));
    return r;
}

// permlane32_swap: ONLY on provably-distinct live values (PV w-words).
// Never on a value and its own copy (rounds 4/5 aliasing bug).
#define PSWAP(a, b) asm("v_permlane32_swap_b32 %0, %1" : "+v"(a), "+v"(b))

__device__ __forceinline__ void load_lds16(const void* g, void* l) {
    __builtin_amdgcn_global_load_lds(
        (const __attribute__((address_space(1))) void*)g,
        (__attribute__((address_space(3))) void*)l, 16, 0, 0);
}

// ---------------------------------------------------------------------------
// Merged f32 -> bf16 conversion: z 0..7 = x (8 chunks), z 8..11 = Wq,Wk,Wv,Wo.
// Wq gets 0.125*log2(e): exp2(S') == exp(q.k/8).  2048 elems/block.
// ---------------------------------------------------------------------------
__global__ __launch_bounds__(256) void cvt_all(const float* __restrict__ x,
                                               const float* __restrict__ wq,
                                               const float* __restrict__ wk,
                                               const float* __restrict__ wv,
                                               const float* __restrict__ wo,
                                               unsigned short* __restrict__ ox,
                                               unsigned short* __restrict__ oq,
                                               unsigned short* __restrict__ ok,
                                               unsigned short* __restrict__ ov,
                                               unsigned short* __restrict__ oo) {
    const int z = blockIdx.y;
    const float* src;
    unsigned short* dst;
    float scale = 1.0f;
    size_t base;
    if (z < 8)       { src = x;  dst = ox; base = (size_t)z * 512 * 2048; }
    else if (z == 8) { src = wq; dst = oq; base = 0; scale = 0.18033688011112042f; }
    else if (z == 9) { src = wk; dst = ok; base = 0; }
    else if (z == 10){ src = wv; dst = ov; base = 0; }
    else             { src = wo; dst = oo; base = 0; }
    size_t i = base + ((size_t)blockIdx.x * 256 + threadIdx.x) * 8;
    float4 a = *(const float4*)(src + i);
    float4 b = *(const float4*)(src + i + 4);
    ushort8 r;
    r[0] = f2bf(a.x*scale); r[1] = f2bf(a.y*scale); r[2] = f2bf(a.z*scale); r[3] = f2bf(a.w*scale);
    r[4] = f2bf(b.x*scale); r[5] = f2bf(b.y*scale); r[6] = f2bf(b.z*scale); r[7] = f2bf(b.w*scale);
    *(ushort8*)(dst + i) = r;
}

// ---------------------------------------------------------------------------
// Shared GEMM body (m97 structure), XCD-swizzled.  LAYOUT 0: f32 C[M][1024];
// 1: bf16 [B,H,S,HD]; 2: bf16 V^T [B,H,HD,S].
// ---------------------------------------------------------------------------
template<int LAYOUT>
__device__ __forceinline__ void gemm_body(const unsigned short* __restrict__ A,
                                          const unsigned short* __restrict__ W,
                                          void* __restrict__ Cout,
                                          unsigned short* As, unsigned short* Bs) {
    const int t    = threadIdx.x;
    const int lane = t & 63, wid = t >> 6;
    const int wr   = wid >> 1, wc = wid & 1;
    const int lrow = lane & 15, lkg = lane >> 4;
    const int lid  = blockIdx.y * 8 + blockIdx.x;
    const int ord  = (lid & 7) * 64 + (lid >> 3);
    const int row0 = (ord >> 3) * 128, col0 = (ord & 7) * 128;

    f32x4 acc[4][4];
    #pragma unroll
    for (int m = 0; m < 4; ++m)
        #pragma unroll
        for (int n = 0; n < 4; ++n) acc[m][n] = (f32x4){0.f, 0.f, 0.f, 0.f};

    const int c0 = t, c1 = t + 256;
    const unsigned short* Ag0 = A + (size_t)(row0 + (c0 >> 2)) * DD + (c0 & 3) * 8;
    const unsigned short* Ag1 = A + (size_t)(row0 + (c1 >> 2)) * DD + (c1 & 3) * 8;
    const unsigned short* Wg0 = W + (size_t)(col0 + (c0 >> 2)) * DD + (c0 & 3) * 8;
    const unsigned short* Wg1 = W + (size_t)(col0 + (c1 >> 2)) * DD + (c1 & 3) * 8;

    auto stage = [&](int buf, int k0) {
        load_lds16(Ag0 + k0, &As[buf*128*32 + c0 * 8]);
        load_lds16(Ag1 + k0, &As[buf*128*32 + c1 * 8]);
        load_lds16(Wg0 + k0, &Bs[buf*128*32 + c0 * 8]);
        load_lds16(Wg1 + k0, &Bs[buf*128*32 + c1 * 8]);
    };

    stage(0, 0);
    __syncthreads();
    for (int kt = 0; kt < DD / 32; ++kt) {
        const int cur = kt & 1;
        if (kt + 1 < DD / 32) stage(cur ^ 1, (kt + 1) * 32);
        bf16x8 af[4], bfr[4];
        #pragma unroll
        for (int m = 0; m < 4; ++m)
            af[m] = *(const bf16x8*)&As[cur*128*32 + (wr*64 + m*16 + lrow) * 32 + lkg*8];
        #pragma unroll
        for (int n = 0; n < 4; ++n)
            bfr[n] = *(const bf16x8*)&Bs[cur*128*32 + (wc*64 + n*16 + lrow) * 32 + lkg*8];
        __builtin_amdgcn_s_setprio(1);
        #pragma unroll
        for (int m = 0; m < 4; ++m)
            #pragma unroll
            for (int n = 0; n < 4; ++n)
                acc[m][n] = __builtin_amdgcn_mfma_f32_16x16x32_bf16(af[m], bfr[n], acc[m][n], 0, 0, 0);
        __builtin_amdgcn_s_setprio(0);
        __syncthreads();
    }

    #pragma unroll
    for (int m = 0; m < 4; ++m) {
        #pragma unroll
        for (int n = 0; n < 4; ++n) {
            if (LAYOUT == 2) {
                int gm0 = row0 + wr*64 + m*16 + lkg*4;
                int gn  = col0 + wc*64 + n*16 + lrow;
                int b_ = gm0 >> 11, s0 = gm0 & 2047;
                int h_ = gn >> 6,  hd = gn & 63;
                ushort4v hv;
                hv[0] = f2bf(acc[m][n][0]); hv[1] = f2bf(acc[m][n][1]);
                hv[2] = f2bf(acc[m][n][2]); hv[3] = f2bf(acc[m][n][3]);
                *(ushort4v*)&((unsigned short*)Cout)[(((size_t)b_*HH + h_)*HDD + hd)*SS + s0] = hv;
            } else {
                #pragma unroll
                for (int j = 0; j < 4; ++j) {
                    int gm = row0 + wr*64 + m*16 + lkg*4 + j;
                    int gn = col0 + wc*64 + n*16 + lrow;
                    float v = acc[m][n][j];
                    if (LAYOUT == 1) {
                        int b_ = gm >> 11, s_ = gm & 2047;
                        int h_ = gn >> 6,  hd = gn & 63;
                        ((unsigned short*)Cout)[(((size_t)b_*HH + h_)*SS + s_)*HDD + hd] = f2bf(v);
                    } else {
                        ((float*)Cout)[(size_t)gm * DD + gn] = v;
                    }
                }
            }
        }
    }
}

__global__ __launch_bounds__(256) void gemm_qkv(const unsigned short* __restrict__ A,
                                                const unsigned short* __restrict__ Wq,
                                                const unsigned short* __restrict__ Wk,
                                                const unsigned short* __restrict__ Wv,
                                                unsigned short* __restrict__ Q,
                                                unsigned short* __restrict__ K,
                                                unsigned short* __restrict__ V) {
    __shared__ unsigned short As[2*128*32];
    __shared__ unsigned short Bs[2*128*32];
    const int z = blockIdx.z;
    if (z == 2)      gemm_body<2>(A, Wv, V, As, Bs);
    else if (z == 1) gemm_body<1>(A, Wk, K, As, Bs);
    else             gemm_body<1>(A, Wq, Q, As, Bs);
}

__global__ __launch_bounds__(256) void gemm_proj(const unsigned short* __restrict__ A,
                                                 const unsigned short* __restrict__ W,
                                                 float* __restrict__ C) {
    __shared__ unsigned short As[2*128*32];
    __shared__ unsigned short Bs[2*128*32];
    gemm_body<0>(A, W, C, As, Bs);
}

// ---------------------------------------------------------------------------
// Flash attention v7 (round-8 proven config, 89 us / MfmaUtil 43%):
// 32x32x16 MFMA, swapped QK^T, exp2 units, no-max softmax, double-q (A,B),
// ones-MFMA row-sum, hoisted zero C-in, KVBLK=64 double-buffered.
// NOTE: KVBLK=128 (round 10) REGRESSED: FETCH_SIZE doubled (L2 reuse window
// across the 8 q-blocks/bh stretched past capacity), MfmaUtil 43->33.  Keep 64.
// ---------------------------------------------------------------------------
__global__ __launch_bounds__(256, 2) void flash_mfma7(const unsigned short* __restrict__ Qg,
                                                      const unsigned short* __restrict__ Kg,
                                                      const unsigned short* __restrict__ Vtg,
                                                      float* __restrict__ outf,
                                                      unsigned short* __restrict__ outb) {
    __shared__ unsigned short Ks[2][64*64];
    __shared__ unsigned short Vs[2][64*64];
    const int t   = threadIdx.x, lane = t & 63, wid = t >> 6;
    const int l31 = lane & 31;
    const int hi  = lane >> 5;
    const int lid = blockIdx.y * 8 + blockIdx.x;
    const int ord = (lid & 7) * 64 + (lid >> 3);
    const int bh  = ord >> 3, b_ = bh >> 4, h_ = bh & 15;
    const int qA  = (ord & 7) * 256 + wid * 32;    // group A rows; B = qA + 128

    const unsigned short* Qb = Qg  + (size_t)bh * SS * HDD;
    const unsigned short* Kb = Kg  + (size_t)bh * SS * HDD;
    const unsigned short* Vb = Vtg + (size_t)bh * HDD * SS;

    bf16x8 qfA[4], qfB[4];
    #pragma unroll
    for (int ks = 0; ks < 4; ++ks) {
        qfA[ks] = *(const bf16x8*)&Qb[(size_t)(qA + l31) * HDD + ks*16 + hi*8];
        qfB[ks] = *(const bf16x8*)&Qb[(size_t)(qA + 128 + l31) * HDD + ks*16 + hi*8];
    }

    f32x16 osA0, osA1, osB0, osB1, sumA, sumB, z;
    #pragma unroll
    for (int r = 0; r < 16; ++r) {
        osA0[r] = 0.f; osA1[r] = 0.f; osB0[r] = 0.f; osB1[r] = 0.f;
        sumA[r] = 0.f; sumB[r] = 0.f; z[r] = 0.f;
    }

    bf16x8 onesf;
    #pragma unroll
    for (int e = 0; e < 8; ++e) onesf[e] = (short)0x3F80;   // bf16 1.0

    const int c0 = t, c1 = t + 256;
    const unsigned sb0 = ((unsigned)(c0 << 4)) ^ ((((unsigned)c0 >> 3) & 7u) << 4);
    const unsigned sb1 = ((unsigned)(c1 << 4)) ^ ((((unsigned)c1 >> 3) & 7u) << 4);
    const unsigned xs  = ((unsigned)(l31 & 7)) << 4;

    bf16x8 kr0, kr1, vr0, vr1;
    kr0 = *(const bf16x8*)&Kb[8*c0];
    kr1 = *(const bf16x8*)&Kb[8*c1];
    vr0 = *(const bf16x8*)&Vb[(size_t)(c0 >> 3) * SS + (c0 & 7) * 8];
    vr1 = *(const bf16x8*)&Vb[(size_t)(c1 >> 3) * SS + (c1 & 7) * 8];
    *(bf16x8*)((char*)&Ks[0][0] + sb0) = kr0;
    *(bf16x8*)((char*)&Ks[0][0] + sb1) = kr1;
    *(bf16x8*)((char*)&Vs[0][0] + sb0) = vr0;
    *(bf16x8*)((char*)&Vs[0][0] + sb1) = vr1;
    __syncthreads();

    for (int kt = 0; kt < SS/64; ++kt) {
        const int cur = kt & 1;
        if (kt + 1 < SS/64) {                       // issue next-tile loads early
            kr0 = *(const bf16x8*)&Kb[(size_t)(kt+1)*4096 + 8*c0];
            kr1 = *(const bf16x8*)&Kb[(size_t)(kt+1)*4096 + 8*c1];
            vr0 = *(const bf16x8*)&Vb[(size_t)(c0 >> 3) * SS + (kt+1)*64 + (c0 & 7) * 8];
            vr1 = *(const bf16x8*)&Vb[(size_t)(c1 >> 3) * SS + (kt+1)*64 + (c1 & 7) * 8];
        }
        const char* Kc = (const char*)&Ks[cur][0];
        const char* Vc = (const char*)&Vs[cur][0];

        // S'^T = mfma(K, Q): each kf pair feeds all 4 accumulators
        f32x16 saA0, saA1, saB0, saB1;
        __builtin_amdgcn_s_setprio(1);
        #pragma unroll
        for (int ks = 0; ks < 4; ++ks) {
            const unsigned cb = ks*32 + hi*16;
            bf16x8 kf0 = *(const bf16x8*)(Kc + (((unsigned)(l31*128)      + cb) ^ xs));
            bf16x8 kf1 = *(const bf16x8*)(Kc + (((unsigned)((32+l31)*128) + cb) ^ xs));
            if (ks == 0) {
                saA0 = __builtin_amdgcn_mfma_f32_32x32x16_bf16(kf0, qfA[0], z, 0, 0, 0);
                saA1 = __builtin_amdgcn_mfma_f32_32x32x16_bf16(kf1, qfA[0], z, 0, 0, 0);
                saB0 = __builtin_amdgcn_mfma_f32_32x32x16_bf16(kf0, qfB[0], z, 0, 0, 0);
                saB1 = __builtin_amdgcn_mfma_f32_32x32x16_bf16(kf1, qfB[0], z, 0, 0, 0);
            } else {
                saA0 = __builtin_amdgcn_mfma_f32_32x32x16_bf16(kf0, qfA[ks], saA0, 0, 0, 0);
                saA1 = __builtin_amdgcn_mfma_f32_32x32x16_bf16(kf1, qfA[ks], saA1, 0, 0, 0);
                saB0 = __builtin_amdgcn_mfma_f32_32x32x16_bf16(kf0, qfB[ks], saB0, 0, 0, 0);
                saB1 = __builtin_amdgcn_mfma_f32_32x32x16_bf16(kf1, qfB[ks], saB1, 0, 0, 0);
            }
        }
        __builtin_amdgcn_s_setprio(0);

        // P = exp2(S') packed straight to bf16 (row-sum via ones-MFMA below)
        unsigned int pkA0[4][2], pkA1[4][2], pkB0[4][2], pkB1[4][2];
        #pragma unroll
        for (int a = 0; a < 4; ++a) {
            #pragma unroll
            for (int h = 0; h < 2; ++h) {
                pkA0[a][h] = cvtpk(EXP2(saA0[4*a + 2*h]), EXP2(saA0[4*a + 2*h + 1]));
                pkA1[a][h] = cvtpk(EXP2(saA1[4*a + 2*h]), EXP2(saA1[4*a + 2*h + 1]));
                pkB0[a][h] = cvtpk(EXP2(saB0[4*a + 2*h]), EXP2(saB0[4*a + 2*h + 1]));
                pkB1[a][h] = cvtpk(EXP2(saB1[4*a + 2*h]), EXP2(saB1[4*a + 2*h + 1]));
            }
        }

        __builtin_amdgcn_s_setprio(1);
        #pragma unroll
        for (int ksg = 0; ksg < 4; ++ksg) {
            const int ks2 = (ksg & 1) * 2;
            unsigned int a0, a1, a2, a3, b0, b1, b2, b3;
            if ((ksg >> 1) == 0) {
                a0 = pkA0[ks2][0]; a2 = pkA0[ks2+1][0]; a1 = pkA0[ks2][1]; a3 = pkA0[ks2+1][1];
                b0 = pkB0[ks2][0]; b2 = pkB0[ks2+1][0]; b1 = pkB0[ks2][1]; b3 = pkB0[ks2+1][1];
            } else {
                a0 = pkA1[ks2][0]; a2 = pkA1[ks2+1][0]; a1 = pkA1[ks2][1]; a3 = pkA1[ks2+1][1];
                b0 = pkB1[ks2][0]; b2 = pkB1[ks2+1][0]; b1 = pkB1[ks2][1]; b3 = pkB1[ks2+1][1];
            }
            PSWAP(a0, a2); PSWAP(a1, a3);
            PSWAP(b0, b2); PSWAP(b1, b3);
            uint4v wa = {a0, a1, a2, a3};
            uint4v wb = {b0, b1, b2, b3};
            bf16x8 pfA = __builtin_bit_cast(bf16x8, wa);
            bf16x8 pfB = __builtin_bit_cast(bf16x8, wb);
            const unsigned cb = ksg*32 + hi*16;
            bf16x8 vf0 = *(const bf16x8*)(Vc + (((unsigned)(l31*128)      + cb) ^ xs));
            bf16x8 vf1 = *(const bf16x8*)(Vc + (((unsigned)((32+l31)*128) + cb) ^ xs));
            osA0 = __builtin_amdgcn_mfma_f32_32x32x16_bf16(vf0, pfA, osA0, 0, 0, 0);
            osA1 = __builtin_amdgcn_mfma_f32_32x32x16_bf16(vf1, pfA, osA1, 0, 0, 0);
            osB0 = __builtin_amdgcn_mfma_f32_32x32x16_bf16(vf0, pfB, osB0, 0, 0, 0);
            osB1 = __builtin_amdgcn_mfma_f32_32x32x16_bf16(vf1, pfB, osB1, 0, 0, 0);
            sumA = __builtin_amdgcn_mfma_f32_32x32x16_bf16(onesf, pfA, sumA, 0, 0, 0);
            sumB = __builtin_amdgcn_mfma_f32_32x32x16_bf16(onesf, pfB, sumB, 0, 0, 0);
        }
        __builtin_amdgcn_s_setprio(0);

        if (kt + 1 < SS/64) {                       // write next tile (other buffer)
            char* Kn = (char*)&Ks[cur ^ 1][0];
            char* Vn = (char*)&Vs[cur ^ 1][0];
            *(bf16x8*)(Kn + sb0) = kr0;
            *(bf16x8*)(Kn + sb1) = kr1;
            *(bf16x8*)(Vn + sb0) = vr0;
            *(bf16x8*)(Vn + sb1) = vr1;
        }
        __syncthreads();
    }

    // epilogue: L[q] = any element of sum acc (all identical by construction)
    #pragma unroll
    for (int g = 0; g < 2; ++g) {
        const float invl = 1.0f / (g == 0 ? sumA[0] : sumB[0]);
        const int   s_   = qA + (g ? 128 : 0) + l31;
        float*          po = outf + (((size_t)b_ * SS + s_) * HH + h_) * HDD;
        unsigned short* pb = outb + (((size_t)b_ * SS + s_) * HH + h_) * HDD;
        #pragma unroll
        for (int a = 0; a < 4; ++a) {
            {
                const f32x16& o = g == 0 ? osA0 : osB0;
                const int d0 = 8*a + 4*hi;
                float4 v; v.x = o[4*a+0]*invl; v.y = o[4*a+1]*invl;
                          v.z = o[4*a+2]*invl; v.w = o[4*a+3]*invl;
                *(float4*)&po[d0] = v;
                ushort4v hv; hv[0]=f2bf(v.x); hv[1]=f2bf(v.y); hv[2]=f2bf(v.z); hv[3]=f2bf(v.w);
                *(ushort4v*)&pb[d0] = hv;
            }
            {
                const f32x16& o = g == 0 ? osA1 : osB1;
                const int d0 = 32 + 8*a + 4*hi;
                float4 v; v.x = o[4*a+0]*invl; v.y = o[4*a+1]*invl;
                          v.z = o[4*a+2]*invl; v.w = o[4*a+3]*invl;
                *(float4*)&po[d0] = v;
                ushort4v hv; hv[0]=f2bf(v.x); hv[1]=f2bf(v.y); hv[2]=f2bf(v.z); hv[3]=f2bf(v.w);
                *(ushort4v*)&pb[d0] = hv;
            }
        }
    }
}

extern "C" void kernel_launch(void* const* d_in, const int* in_sizes, int n_in,
                              void* d_out, int out_size, void* d_ws, size_t ws_size,
                              hipStream_t stream) {
    const float* x  = (const float*)d_in[0];
    const float* Wq = (const float*)d_in[1];
    const float* Wk = (const float*)d_in[2];
    const float* Wv = (const float*)d_in[3];
    const float* Wo = (const float*)d_in[4];
    float* out      = (float*)d_out;
    float* per_head = out + (size_t)MM * DD;

    unsigned short* ws   = (unsigned short*)d_ws;
    const size_t NE = (size_t)MM * DD;        // 8M elements
    unsigned short* Qbf  = ws;
    unsigned short* Kbf  = Qbf + NE;
    unsigned short* Vbf  = Kbf + NE;          // V^T [B,H,HD,S]
    unsigned short* xbf  = Vbf + NE;
    unsigned short* wqbf = xbf + NE;
    unsigned short* wkbf = wqbf + (size_t)DD * DD;
    unsigned short* wvbf = wkbf + (size_t)DD * DD;
    unsigned short* wobf = wvbf + (size_t)DD * DD;
    unsigned short* cbf  = wobf + (size_t)DD * DD;

    cvt_all<<<dim3(512, 12), 256, 0, stream>>>(x, Wq, Wk, Wv, Wo,
                                               xbf, wqbf, wkbf, wvbf, wobf);

    gemm_qkv<<<dim3(DD / 128, MM / 128, 3), 256, 0, stream>>>(xbf, wqbf, wkbf, wvbf,
                                                              Qbf, Kbf, Vbf);

    flash_mfma7<<<dim3(8, BB * HH), 256, 0, stream>>>(Qbf, Kbf, Vbf, per_head, cbf);

    gemm_proj<<<dim3(DD / 128, MM / 128), 256, 0, stream>>>(cbf, wobf, out);
}